// Round 1
// 115.214 us; speedup vs baseline: 1.0363x; 1.0363x over previous
//
#include <hip/hip_runtime.h>
#include <hip/hip_bf16.h>
#include <math.h>

#define HF 96
#define WF 160
#define CH 100
#define HH 48      // HF/2
#define HW 80      // WF/2
#define NPIX 3840  // HH*HW
#define MD 9
#define KD 19
#define K2 361
#define NMAX 8

// ws float offsets. Deliberate overlap-guards: OOB-masked reads off Yt/ys edges
// land in the neighboring arrays (values unused — mask selects 1.0).
// Max stray from Yt window reads is now +10 / -9 floats (cbase in [-9,70], d<=9,
// c<=99, rcl<=47) -> lands in xs / Xt tail respectively. Guarded by layout.
#define OFF_XT 0
#define OFF_YT (CH*NPIX)               // 384000
#define OFF_XS (2*CH*NPIX)             // 768000
#define OFF_YS (2*CH*NPIX + NPIX)      // 771840
#define OFF_DH (2*CH*NPIX + 2*NPIX)    // 775680  (bf16, k-major: [K2][NPIX])

// ---------------- Kernel A: pool + norms, channel-major, shuffle-reduced ------
// 4 waves/block, one half-res pixel per wave, no barriers. Grid = 960.
__global__ __launch_bounds__(256) void pool_kernel(
    const float* __restrict__ q, const float* __restrict__ p,
    float* __restrict__ Xt, float* __restrict__ Yt,
    float* __restrict__ xs, float* __restrict__ ys) {
  int w = threadIdx.x >> 6, L = threadIdx.x & 63;
  int pix = blockIdx.x * 4 + w;
  int i = pix / HW, j = pix - i * HW;
  int base = (2 * i) * WF * CH + (2 * j) * CH;
  float nx = 0.f, ny = 0.f;
  for (int c = L; c < CH; c += 64) {
    int b = base + c;
    float xv = 0.25f * (q[b] + q[b + CH] + q[b + WF * CH] + q[b + WF * CH + CH]);
    float yv = 0.25f * (p[b] + p[b + CH] + p[b + WF * CH] + p[b + WF * CH + CH]);
    Xt[c * NPIX + pix] = xv;
    Yt[c * NPIX + pix] = yv;
    nx = fmaf(xv, xv, nx);
    ny = fmaf(yv, yv, ny);
  }
  for (int s = 32; s > 0; s >>= 1) {
    nx += __shfl_down(nx, s);
    ny += __shfl_down(ny, s);
  }
  if (L == 0) { xs[pix] = nx; ys[pix] = ny; }
}

// ---------------- Kernel B: pure-register local correlation, row-paired -------
// Key reuse: output (row i, dy) and output (row i+1, dy-1) consume the SAME
// Y row r = i+dy-9 and the same dx window; only X differs. One thread computes
// both: acc[2][10] fed by 12 loads/c (2 X + 10 shared Y) instead of 22 for the
// same 20 FMAs -> ~1.8x less L1 traffic (the old per-thread sliding window
// moved 2816 B/wave/c through L1 for ~550 B unique).
// Thread = (row-pair column slot t, dy-pair dp, dx-half h). Lanes = consecutive
// columns -> stride-1 coalesced. Fully-OOB rows exit before the c-loop.
// Grid = (1920/128, 40).
__global__ __launch_bounds__(128) void dist_kernel(
    const float* __restrict__ Xt, const float* __restrict__ Yt,
    const float* __restrict__ xs, const float* __restrict__ ys,
    __hip_bfloat16* __restrict__ dh2) {
  int t = blockIdx.x * 128 + threadIdx.x;   // 0..1919: (row-pair, col)
  int u = blockIdx.y;                        // 0..39
  int dp = u >> 1, h = u & 1;                // dp = 0..19 (dy-pair index)
  int ip = t / HW, j = t - ip * HW;          // ip = 0..23
  int iA = 2 * ip;                           // even row of the pair
  int pixA = iA * HW + j, pixB = pixA + HW;  // rows iA, iA+1

  bool doA = (dp < KD);                      // output A: (row iA,   dy = dp)
  bool doB = (dp >= 1);                      // output B: (row iA+1, dy = dp-1)
  int r = iA + dp - MD;                      // shared Y row for both outputs
  bool rowOK = (r >= 0 && r < HH);
  int cbase = j - MD + 10 * h;
  int nd = h ? 9 : 10;
  int kbA = dp * KD + 10 * h;
  int kbB = (dp - 1) * KD + 10 * h;

  if (!rowOK) {
    // Entire window row out of range -> all outputs exactly 1.0 (matches
    // reference PAD_VAL saturation). Skip the 100-iter loop.
    __hip_bfloat16 one = __float2bfloat16(1.0f);
#pragma unroll
    for (int d = 0; d < 10; ++d) {
      if (d >= nd) break;
      if (doA) dh2[(kbA + d) * NPIX + pixA] = one;
      if (doB) dh2[(kbB + d) * NPIX + pixB] = one;
    }
    return;
  }

  float accA[10], accB[10];
#pragma unroll
  for (int d = 0; d < 10; ++d) { accA[d] = 0.f; accB[d] = 0.f; }

  const float* xpA = Xt + pixA;
  const float* xpB = Xt + pixB;
  const float* yp  = Yt + r * HW + cbase;    // may stray <=10 floats OOB: lands
                                             // in adjacent ws array, value masked.
#pragma unroll 2
  for (int c = 0; c < CH; ++c) {
    float xa = *xpA, xb = *xpB;
#pragma unroll
    for (int d = 0; d < 10; ++d) {
      float yv = yp[d];
      accA[d] = fmaf(xa, yv, accA[d]);
      accB[d] = fmaf(xb, yv, accB[d]);
    }
    xpA += NPIX; xpB += NPIX; yp += NPIX;
  }

  float xssA = xs[pixA];
  float xssB = xs[pixB];
  const float* ysr = ys + r * HW;
#pragma unroll
  for (int d = 0; d < 10; ++d) {
    if (d >= nd) break;
    int jj = cbase + d;
    bool okc = (jj >= 0) && (jj < HW);
    int jcl = jj < 0 ? 0 : (jj > HW - 1 ? HW - 1 : jj);
    float yss = ysr[jcl];
    if (doA) {
      float s = xssA + yss - 2.f * accA[d];
      float e = __expf(-s);
      float rv = okc ? (1.f - e) / (1.f + e) : 1.0f;
      dh2[(kbA + d) * NPIX + pixA] = __float2bfloat16(rv);
    }
    if (doB) {
      float s = xssB + yss - 2.f * accB[d];
      float e = __expf(-s);
      float rv = okc ? (1.f - e) / (1.f + e) : 1.0f;
      dh2[(kbB + d) * NPIX + pixB] = __float2bfloat16(rv);
    }
  }
}

// ---------------- Kernel C: bilinear upsample + masked min (bf16, k-major) ----
// Templated on N (runtime-n arrays demote to scratch: R4, VGPR=20, 70us).
// Block = 1024 thr = 16 waves over the SAME 64 pixels, k split 16 ways;
// LDS min-combine. Grid = 240 blocks.
template <int N>
__global__ __launch_bounds__(1024) void upmin_kernel(
    const __hip_bfloat16* __restrict__ dh2, const int* __restrict__ labels,
    const int* __restrict__ gt, float* __restrict__ out) {
  int w = threadIdx.x >> 6;        // 0..15: k-slice
  int lane = threadIdx.x & 63;     // pixel within strip
  int pixel = blockIdx.x * 64 + lane;
  int I = pixel / WF, J = pixel - I * WF;

  const float sy = (float)((HH - 1.0) / (HF - 1.0));
  const float sx = (float)((HW - 1.0) / (WF - 1.0));
  float py = (float)I * sy;
  int y0 = (int)floorf(py); if (y0 > HH - 2) y0 = HH - 2; if (y0 < 0) y0 = 0;
  float fy = py - (float)y0;
  float px = (float)J * sx;
  int x0 = (int)floorf(px); if (x0 > HW - 2) x0 = HW - 2; if (x0 < 0) x0 = 0;
  float fx = px - (float)x0;
  float w00 = (1.f - fy) * (1.f - fx), w01 = (1.f - fy) * fx;
  float w10 = fy * (1.f - fx),         w11 = fy * fx;
  int np00 = y0 * HW + x0;

  int gtl[N];
  float mins[N];
#pragma unroll
  for (int o = 0; o < N; ++o) { gtl[o] = gt[o]; mins[o] = 1.0f; }

  for (int k = w; k < K2; k += 16) {
    int dy = k / KD, dx = k - dy * KD;
    int P = I + dy - MD, Q = J + dx - MD;
    const __hip_bfloat16* dk = dh2 + k * NPIX + np00;
    float v = w00 * __bfloat162float(dk[0]) + w01 * __bfloat162float(dk[1]) +
              w10 * __bfloat162float(dk[HW]) + w11 * __bfloat162float(dk[HW + 1]);
    if (P >= 0 && P < HF && Q >= 0 && Q < WF) {
      int lab = labels[P * WF + Q];
#pragma unroll
      for (int o = 0; o < N; ++o)
        if (lab == gtl[o]) mins[o] = fminf(mins[o], v);
    }
  }

  __shared__ float mm[16][64][N];
#pragma unroll
  for (int o = 0; o < N; ++o) mm[w][lane][o] = mins[o];
  __syncthreads();
  if (w < 8) {
#pragma unroll
    for (int o = 0; o < N; ++o)
      mm[w][lane][o] = fminf(mm[w][lane][o], mm[w + 8][lane][o]);
  }
  __syncthreads();
  if (w < 4) {
#pragma unroll
    for (int o = 0; o < N; ++o)
      mm[w][lane][o] = fminf(mm[w][lane][o], mm[w + 4][lane][o]);
  }
  __syncthreads();
  if (w == 0) {
#pragma unroll
    for (int o = 0; o < N; ++o) {
      float m = fminf(fminf(mm[0][lane][o], mm[1][lane][o]),
                      fminf(mm[2][lane][o], mm[3][lane][o]));
      out[pixel * N + o] = m;
    }
  }
}

extern "C" void kernel_launch(void* const* d_in, const int* in_sizes, int n_in,
                              void* d_out, int out_size, void* d_ws, size_t ws_size,
                              hipStream_t stream) {
  const float* prev  = (const float*)d_in[0];   // prev_frame_embedding -> y
  const float* query = (const float*)d_in[1];   // query_embedding      -> x
  const int* labels  = (const int*)d_in[2];
  const int* gt      = (const int*)d_in[3];
  int n = in_sizes[3];
  if (n > NMAX) n = NMAX;
  float* ws = (float*)d_ws;
  float* Xt = ws + OFF_XT;
  float* Yt = ws + OFF_YT;
  float* xs = ws + OFF_XS;
  float* ys = ws + OFF_YS;
  __hip_bfloat16* dh2 = (__hip_bfloat16*)(ws + OFF_DH);
  float* out = (float*)d_out;

  hipLaunchKernelGGL(pool_kernel, dim3(NPIX / 4), dim3(256), 0, stream,
                     query, prev, Xt, Yt, xs, ys);
  hipLaunchKernelGGL(dist_kernel, dim3(1920 / 128, 40), dim3(128), 0, stream,
                     Xt, Yt, xs, ys, dh2);
  dim3 ug(HF * WF / 64), ub(1024);
  switch (n) {
    case 1: hipLaunchKernelGGL(upmin_kernel<1>, ug, ub, 0, stream, dh2, labels, gt, out); break;
    case 2: hipLaunchKernelGGL(upmin_kernel<2>, ug, ub, 0, stream, dh2, labels, gt, out); break;
    case 3: hipLaunchKernelGGL(upmin_kernel<3>, ug, ub, 0, stream, dh2, labels, gt, out); break;
    case 4: hipLaunchKernelGGL(upmin_kernel<4>, ug, ub, 0, stream, dh2, labels, gt, out); break;
    case 5: hipLaunchKernelGGL(upmin_kernel<5>, ug, ub, 0, stream, dh2, labels, gt, out); break;
    case 6: hipLaunchKernelGGL(upmin_kernel<6>, ug, ub, 0, stream, dh2, labels, gt, out); break;
    case 7: hipLaunchKernelGGL(upmin_kernel<7>, ug, ub, 0, stream, dh2, labels, gt, out); break;
    default: hipLaunchKernelGGL(upmin_kernel<8>, ug, ub, 0, stream, dh2, labels, gt, out); break;
  }
}